// Round 4
// baseline (523.550 us; speedup 1.0000x reference)
//
#include <hip/hip_runtime.h>
#include <hip/hip_bf16.h>

namespace {
constexpr int kN    = 8192;
constexpr int kFin  = 512;
constexpr int kFout = 64;
constexpr float kAlpha = 0.2f;
constexpr int kJSplit = 4;                  // j-range split for k_attn
constexpr int kJLen   = kN / kJSplit;       // 2048
constexpr int kChunks = kJLen / 128;        // 16

using bf16x8 = __attribute__((ext_vector_type(8))) short;
using f32x4  = __attribute__((ext_vector_type(4))) float;

__device__ __forceinline__ unsigned short f2bf(float x) {
  return __builtin_bit_cast(unsigned short, __float2bfloat16(x));
}
__device__ __forceinline__ float lrelu(float x) {
  return fmaxf(x, kAlpha * x);   // valid since 0<alpha<1
}
// monotone float<->uint order-preserving map (for atomicMax on float)
__device__ __forceinline__ unsigned int fkey(float x) {
  unsigned int b = __float_as_uint(x);
  return (b & 0x80000000u) ? ~b : (b | 0x80000000u);
}
__device__ __forceinline__ float fdec(unsigned int k) {
  return (k & 0x80000000u) ? __uint_as_float(k ^ 0x80000000u) : __uint_as_float(~k);
}
} // namespace

// ---------------------------------------------------------------------------
// k_wt: WT[f][k] = W[k][f]; thread 0 zero-inits the s_dst-max atomic slot.
// ---------------------------------------------------------------------------
__global__ __launch_bounds__(256) void k_wt(const float* __restrict__ W,
                                            float* __restrict__ WT,
                                            unsigned int* __restrict__ Smax_u) {
  const int gid = blockIdx.x * 256 + threadIdx.x;   // 0..32767
  if (gid == 0) *Smax_u = 0u;                       // < fkey(any finite)
  const int k = gid >> 6, f = gid & 63;
  WT[(size_t)f * kFin + k] = W[gid];
}

// ---------------------------------------------------------------------------
// k_linear: h = X@W (fp32); s_src/s_dst (+ global max of s_dst via atomicMax);
// h emitted as hTf in MFMA-B-fragment order:
//   element ((jblk*4 + w)*64 + lane)*8 + e  =  h[jblk*32 + (lane>>4)*8 + e][w*16 + (lane&15)]
// grid 512 x 256: block = 16 rows. X tile bulk-staged to LDS (latency paid
// once); WT streamed from L2 with depth-2 register prefetch.
// ---------------------------------------------------------------------------
__global__ __launch_bounds__(256) void k_linear(
    const float* __restrict__ X, const float* __restrict__ WT, const float* __restrict__ A,
    unsigned short* __restrict__ hTf, float* __restrict__ s_src, float* __restrict__ s_dst,
    unsigned int* __restrict__ Smax_u)
{
  const int t = threadIdx.x;
  const int wv = t >> 6, f = t & 63;
  const int i0 = blockIdx.x * 16;

  __shared__ float Xlds[16 * kFin];          // 32 KB
  __shared__ unsigned short h_sm[16][64];    // 2 KB
  __shared__ float red[4];

  // ---- bulk-stage X tile: 8 outstanding float4 per thread ----
  {
    const float4* Xg = (const float4*)(X + (size_t)i0 * kFin);
    float4* Xl = (float4*)Xlds;
    float4 v[8];
#pragma unroll
    for (int i = 0; i < 8; ++i) v[i] = Xg[t + i * 256];
#pragma unroll
    for (int i = 0; i < 8; ++i) Xl[t + i * 256] = v[i];
  }
  __syncthreads();

  // ---- compute 4 rows per wave, lane = output feature ----
  const int r0l = wv * 4;                    // local row base
  const float* w0 = WT + (size_t)f * kFin;
  float acc0 = 0.f, acc1 = 0.f, acc2 = 0.f, acc3 = 0.f;
  float4 wb0 = *(const float4*)(w0 + 0);
  float4 wb1 = *(const float4*)(w0 + 4);
  const float* xr = Xlds + r0l * kFin;
  for (int k = 0; k < kFin; k += 4) {
    const float4 wc = (k & 4) ? wb1 : wb0;
    if (k + 8 < kFin) {
      const float4 wn = *(const float4*)(w0 + k + 8);
      if (k & 4) wb1 = wn; else wb0 = wn;
    }
    const float4 xa = *(const float4*)(xr + k);
    const float4 xb = *(const float4*)(xr + kFin + k);
    const float4 xc = *(const float4*)(xr + 2 * kFin + k);
    const float4 xd = *(const float4*)(xr + 3 * kFin + k);
#pragma unroll
    for (int j = 0; j < 4; ++j) {
      const float wk = ((const float*)&wc)[j];
      acc0 = fmaf(((const float*)&xa)[j], wk, acc0);
      acc1 = fmaf(((const float*)&xb)[j], wk, acc1);
      acc2 = fmaf(((const float*)&xc)[j], wk, acc2);
      acc3 = fmaf(((const float*)&xd)[j], wk, acc3);
    }
  }

  // ---- scores + per-wave s_dst max ----
  const float asrc = A[f], adst = A[kFout + f];
  float accs[4] = {acc0, acc1, acc2, acc3};
  float dmax = -3.4e38f;
#pragma unroll
  for (int r = 0; r < 4; ++r) {
    float vs = accs[r] * asrc;
    float vd = accs[r] * adst;
#pragma unroll
    for (int off = 32; off > 0; off >>= 1) {
      vs += __shfl_xor(vs, off, 64);
      vd += __shfl_xor(vd, off, 64);
    }
    if (f == 0) {
      s_src[i0 + r0l + r] = vs;
      s_dst[i0 + r0l + r] = vd;
      dmax = fmaxf(dmax, vd);
    }
    h_sm[r0l + r][f] = f2bf(accs[r]);
  }
  if (f == 0) red[wv] = dmax;
  __syncthreads();
  if (t == 0) {
    float m = fmaxf(fmaxf(red[0], red[1]), fmaxf(red[2], red[3]));
    atomicMax(Smax_u, fkey(m));
  }

  // ---- emit 2 KB hTf fragment slice, coalesced ----
  if (t < 128) {
    const int jblk = i0 >> 5, half = (i0 >> 4) & 1;
    const int w = t >> 5, li = t & 31;
    const int lane = half * 32 + li;
    const int ql = li >> 4, fcol = w * 16 + (li & 15);
    bf16x8 v;
#pragma unroll
    for (int e = 0; e < 8; ++e) v[e] = (short)h_sm[ql * 8 + e][fcol];
    *(bf16x8*)(hTf + (size_t)jblk * 2048 + w * 512 + (size_t)lane * 8) = v;
  }
}

// ---------------------------------------------------------------------------
// k_attn: partial fused mask+softmax+PV over a quarter j-range.
// grid 2048 (512 row-blocks x 4 quarters) x 256. BJ=128, 16 chunks.
// Depth-2 register prefetch of adj/s_dst (cover ~2 chunk iterations);
// hTf B-fragments loaded pre-barrier (cover = barrier); one barrier/chunk
// via P double-buffer. Outputs fp32 partials accp/lp.
// NOTE r4 fix: aptr is int4* -> chunk c lives at aptr[c*32], not aptr[c*8].
// ---------------------------------------------------------------------------
__global__ __launch_bounds__(256) void k_attn(
    const int* __restrict__ adj, const unsigned short* __restrict__ hTf,
    const float* __restrict__ s_src, const float* __restrict__ s_dst,
    const unsigned int* __restrict__ Smax_u, float* __restrict__ accp,
    float* __restrict__ lp)
{
  const int t = threadIdx.x;
  const int wv = t >> 6, lane = t & 63;
  const int b = blockIdx.x;
  const int i0 = (b >> 2) * 16;
  const int jbase = (b & 3) * kJLen;
  const int pr = t >> 4, jb = t & 15;

  __shared__ unsigned short Plds[2][16][136];   // 8.7 KB

  const float S = fdec(*Smax_u);
  const float ssrc = s_src[i0 + pr];
  const float mr = lrelu(ssrc + S);             // >= every score in the row

  float l_acc = 0.f;
  f32x4 acc = {0.f, 0.f, 0.f, 0.f};

  const int4*   aptr = (const int4*)(adj + (size_t)(i0 + pr) * kN + jbase + jb * 8);
  const float4* dptr = (const float4*)(s_dst + jbase + jb * 8);
  const unsigned short* hbase = hTf + (size_t)(jbase >> 5) * 2048 + wv * 512 + (size_t)lane * 8;

  int4 A0[2], A1[2]; float4 D0[2], D1[2];
#pragma unroll
  for (int s = 0; s < 2; ++s) {   // chunks 0 and 1
    A0[s] = aptr[s * 32]; A1[s] = aptr[s * 32 + 1];
    D0[s] = dptr[s * 32]; D1[s] = dptr[s * 32 + 1];
  }

  const int mrow = lane & 15, quad = lane >> 4;
  for (int c = 0; c < kChunks; ++c) {
    const int s = c & 1;
    float pv[8];
    {
      const int* aa = (const int*)&A0[s];
      const float* dd = (const float*)&D0[s];
#pragma unroll
      for (int j = 0; j < 4; ++j) {
        const float e = lrelu(ssrc + dd[j]);
        pv[j] = aa[j] > 0 ? __expf(e - mr) : 0.f;
      }
      aa = (const int*)&A1[s]; dd = (const float*)&D1[s];
#pragma unroll
      for (int j = 0; j < 4; ++j) {
        const float e = lrelu(ssrc + dd[j]);
        pv[4 + j] = aa[j] > 0 ? __expf(e - mr) : 0.f;
      }
    }
    bf16x8 ps;
#pragma unroll
    for (int j = 0; j < 8; ++j) {
      l_acc += pv[j];
      ps[j] = (short)f2bf(pv[j]);
    }
    *(bf16x8*)&Plds[s][pr][jb * 8] = ps;

    // B-fragments for this chunk: issued pre-barrier, used post-barrier
    uint4 hv0 = *(const uint4*)(hbase + (size_t)(c * 4 + 0) * 2048);
    uint4 hv1 = *(const uint4*)(hbase + (size_t)(c * 4 + 1) * 2048);
    uint4 hv2 = *(const uint4*)(hbase + (size_t)(c * 4 + 2) * 2048);
    uint4 hv3 = *(const uint4*)(hbase + (size_t)(c * 4 + 3) * 2048);

    // depth-2 adj/s_dst prefetch (for chunk c+2, into slot s)
    if (c + 2 < kChunks) {
      A0[s] = aptr[(c + 2) * 32]; A1[s] = aptr[(c + 2) * 32 + 1];
      D0[s] = dptr[(c + 2) * 32]; D1[s] = dptr[(c + 2) * 32 + 1];
    }
    __syncthreads();

    acc = __builtin_amdgcn_mfma_f32_16x16x32_bf16(
        *(const bf16x8*)&Plds[s][mrow][0 * 32 + quad * 8], __builtin_bit_cast(bf16x8, hv0), acc, 0, 0, 0);
    acc = __builtin_amdgcn_mfma_f32_16x16x32_bf16(
        *(const bf16x8*)&Plds[s][mrow][1 * 32 + quad * 8], __builtin_bit_cast(bf16x8, hv1), acc, 0, 0, 0);
    acc = __builtin_amdgcn_mfma_f32_16x16x32_bf16(
        *(const bf16x8*)&Plds[s][mrow][2 * 32 + quad * 8], __builtin_bit_cast(bf16x8, hv2), acc, 0, 0, 0);
    acc = __builtin_amdgcn_mfma_f32_16x16x32_bf16(
        *(const bf16x8*)&Plds[s][mrow][3 * 32 + quad * 8], __builtin_bit_cast(bf16x8, hv3), acc, 0, 0, 0);
    // no second barrier: next iteration writes the other P buffer
  }

  // partial denominator: 16 lanes (same pr) reduce
  float lv = l_acc;
  lv += __shfl_xor(lv, 8, 64);
  lv += __shfl_xor(lv, 4, 64);
  lv += __shfl_xor(lv, 2, 64);
  lv += __shfl_xor(lv, 1, 64);
  if (jb == 0) lp[(size_t)b * 16 + pr] = lv;

  // partial PV tile: accp[b][row][col], row = quad*4+reg, col = wv*16+mrow
  float* ab = accp + (size_t)b * 16 * 64;
#pragma unroll
  for (int reg = 0; reg < 4; ++reg) {
    ab[(quad * 4 + reg) * 64 + wv * 16 + mrow] = acc[reg];
  }
}

// ---------------------------------------------------------------------------
// k_comb: out[i][f] = elu( (sum_q accp) / (sum_q lp) )
// ---------------------------------------------------------------------------
__global__ __launch_bounds__(256) void k_comb(const float* __restrict__ accp,
                                              const float* __restrict__ lp,
                                              float* __restrict__ out)
{
  const int gid = blockIdx.x * 256 + threadIdx.x;   // 0..524287
  const int i = gid >> 6, f = gid & 63;
  const int ib = i >> 4, il = i & 15;
  const int b0 = ib * kJSplit;
  float a = 0.f, l = 0.f;
#pragma unroll
  for (int q = 0; q < kJSplit; ++q) {
    a += accp[((size_t)(b0 + q) * 16 + il) * 64 + f];
    l += lp[(size_t)(b0 + q) * 16 + il];
  }
  float v = a / l;
  v = v > 0.f ? v : __expf(v) - 1.f;
  out[gid] = v;
}

extern "C" void kernel_launch(void* const* d_in, const int* in_sizes, int n_in,
                              void* d_out, int out_size, void* d_ws, size_t ws_size,
                              hipStream_t stream) {
  const float* X   = (const float*)d_in[0];   // [8192][512]
  const int*   adj = (const int*)d_in[1];     // [8192][8192]
  const float* W   = (const float*)d_in[2];   // [512][64]
  const float* A   = (const float*)d_in[3];   // [128]
  float* out = (float*)d_out;                 // [8192][64] fp32

  char* ws = (char*)d_ws;
  unsigned short* hTf = (unsigned short*)ws;  ws += (size_t)kN * kFout * 2;    // 1 MB
  float* WT    = (float*)ws;                  ws += (size_t)kFout * kFin * 4;  // 128 KB
  float* s_src = (float*)ws;                  ws += kN * 4;
  float* s_dst = (float*)ws;                  ws += kN * 4;
  unsigned int* Smax_u = (unsigned int*)ws;   ws += 256;
  float* accp  = (float*)ws;                  ws += (size_t)(kN / 16) * kJSplit * 16 * 64 * 4; // 8 MB
  float* lp    = (float*)ws;                  // 128 KB

  k_wt    <<<kFin * kFout / 256, 256, 0, stream>>>(W, WT, Smax_u);
  k_linear<<<kN / 16, 256, 0, stream>>>(X, WT, A, hTf, s_src, s_dst, Smax_u);
  k_attn  <<<(kN / 16) * kJSplit, 256, 0, stream>>>(adj, hTf, s_src, s_dst, Smax_u, accp, lp);
  k_comb  <<<kN * kFout / 256, 256, 0, stream>>>(accp, lp, out);
}

// Round 5
// 412.511 us; speedup vs baseline: 1.2692x; 1.2692x over previous
//
#include <hip/hip_runtime.h>
#include <hip/hip_bf16.h>

namespace {
constexpr int kN    = 8192;
constexpr int kFin  = 512;
constexpr int kFout = 64;
constexpr float kAlpha = 0.2f;
constexpr int kJSplit = 4;                  // j-range split for k_attn
constexpr int kJLen   = kN / kJSplit;       // 2048
constexpr int kChunks = kJLen / 128;        // 16

using bf16x8 = __attribute__((ext_vector_type(8))) short;
using f32x4  = __attribute__((ext_vector_type(4))) float;

__device__ __forceinline__ unsigned short f2bf(float x) {
  return __builtin_bit_cast(unsigned short, __float2bfloat16(x));
}
__device__ __forceinline__ float lrelu(float x) {
  return fmaxf(x, kAlpha * x);   // valid since 0<alpha<1
}
// monotone float<->uint order-preserving map (for atomicMax on float)
__device__ __forceinline__ unsigned int fkey(float x) {
  unsigned int b = __float_as_uint(x);
  return (b & 0x80000000u) ? ~b : (b | 0x80000000u);
}
__device__ __forceinline__ float fdec(unsigned int k) {
  return (k & 0x80000000u) ? __uint_as_float(k ^ 0x80000000u) : __uint_as_float(~k);
}
} // namespace

// ---------------------------------------------------------------------------
// k_wt: WT[f][k] = W[k][f]; thread 0 zero-inits the s_dst-max atomic slot.
// ---------------------------------------------------------------------------
__global__ __launch_bounds__(256) void k_wt(const float* __restrict__ W,
                                            float* __restrict__ WT,
                                            unsigned int* __restrict__ Smax_u) {
  const int gid = blockIdx.x * 256 + threadIdx.x;   // 0..32767
  if (gid == 0) *Smax_u = 0u;                       // < fkey(any finite)
  const int k = gid >> 6, f = gid & 63;
  WT[(size_t)f * kFin + k] = W[gid];
}

// ---------------------------------------------------------------------------
// k_linear: h = X@W (fp32); s_src/s_dst (+ global max of s_dst via atomicMax);
// h emitted as hTf in MFMA-B-fragment order:
//   element ((jblk*4 + w)*64 + lane)*8 + e  =  h[jblk*32 + (lane>>4)*8 + e][w*16 + (lane&15)]
// grid 512 x 256: block = 16 rows. X tile bulk-staged to LDS; WT streamed
// from L2 with depth-2 register prefetch. (Unchanged from r4 — passed.)
// ---------------------------------------------------------------------------
__global__ __launch_bounds__(256) void k_linear(
    const float* __restrict__ X, const float* __restrict__ WT, const float* __restrict__ A,
    unsigned short* __restrict__ hTf, float* __restrict__ s_src, float* __restrict__ s_dst,
    unsigned int* __restrict__ Smax_u)
{
  const int t = threadIdx.x;
  const int wv = t >> 6, f = t & 63;
  const int i0 = blockIdx.x * 16;

  __shared__ float Xlds[16 * kFin];          // 32 KB
  __shared__ unsigned short h_sm[16][64];    // 2 KB
  __shared__ float red[4];

  // ---- bulk-stage X tile: 8 outstanding float4 per thread ----
  {
    const float4* Xg = (const float4*)(X + (size_t)i0 * kFin);
    float4* Xl = (float4*)Xlds;
    float4 v0 = Xg[t +   0], v1 = Xg[t + 256], v2 = Xg[t +  512], v3 = Xg[t +  768];
    float4 v4 = Xg[t +1024], v5 = Xg[t +1280], v6 = Xg[t + 1536], v7 = Xg[t + 1792];
    Xl[t +    0] = v0; Xl[t +  256] = v1; Xl[t +  512] = v2; Xl[t +  768] = v3;
    Xl[t + 1024] = v4; Xl[t + 1280] = v5; Xl[t + 1536] = v6; Xl[t + 1792] = v7;
  }
  __syncthreads();

  // ---- compute 4 rows per wave, lane = output feature ----
  const int r0l = wv * 4;                    // local row base
  const float* w0 = WT + (size_t)f * kFin;
  float acc0 = 0.f, acc1 = 0.f, acc2 = 0.f, acc3 = 0.f;
  float4 wb0 = *(const float4*)(w0 + 0);
  float4 wb1 = *(const float4*)(w0 + 4);
  const float* xr = Xlds + r0l * kFin;
  for (int k = 0; k < kFin; k += 4) {
    const float4 wc = (k & 4) ? wb1 : wb0;
    if (k + 8 < kFin) {
      const float4 wn = *(const float4*)(w0 + k + 8);
      if (k & 4) wb1 = wn; else wb0 = wn;
    }
    const float4 xa = *(const float4*)(xr + k);
    const float4 xb = *(const float4*)(xr + kFin + k);
    const float4 xc = *(const float4*)(xr + 2 * kFin + k);
    const float4 xd = *(const float4*)(xr + 3 * kFin + k);
#pragma unroll
    for (int j = 0; j < 4; ++j) {
      const float wk = ((const float*)&wc)[j];
      acc0 = fmaf(((const float*)&xa)[j], wk, acc0);
      acc1 = fmaf(((const float*)&xb)[j], wk, acc1);
      acc2 = fmaf(((const float*)&xc)[j], wk, acc2);
      acc3 = fmaf(((const float*)&xd)[j], wk, acc3);
    }
  }

  // ---- scores + per-wave s_dst max ----
  const float asrc = A[f], adst = A[kFout + f];
  float accs[4] = {acc0, acc1, acc2, acc3};
  float dmax = -3.4e38f;
#pragma unroll
  for (int r = 0; r < 4; ++r) {
    float vs = accs[r] * asrc;
    float vd = accs[r] * adst;
#pragma unroll
    for (int off = 32; off > 0; off >>= 1) {
      vs += __shfl_xor(vs, off, 64);
      vd += __shfl_xor(vd, off, 64);
    }
    if (f == 0) {
      s_src[i0 + r0l + r] = vs;
      s_dst[i0 + r0l + r] = vd;
      dmax = fmaxf(dmax, vd);
    }
    h_sm[r0l + r][f] = f2bf(accs[r]);
  }
  if (f == 0) red[wv] = dmax;
  __syncthreads();
  if (t == 0) {
    float m = fmaxf(fmaxf(red[0], red[1]), fmaxf(red[2], red[3]));
    atomicMax(Smax_u, fkey(m));
  }

  // ---- emit 2 KB hTf fragment slice, coalesced ----
  if (t < 128) {
    const int jblk = i0 >> 5, half = (i0 >> 4) & 1;
    const int w = t >> 5, li = t & 31;
    const int lane = half * 32 + li;
    const int ql = li >> 4, fcol = w * 16 + (li & 15);
    bf16x8 v;
#pragma unroll
    for (int e = 0; e < 8; ++e) v[e] = (short)h_sm[ql * 8 + e][fcol];
    *(bf16x8*)(hTf + (size_t)jblk * 2048 + w * 512 + (size_t)lane * 8) = v;
  }
}

// ---------------------------------------------------------------------------
// k_attn: partial fused mask+softmax+PV over a quarter j-range.
// grid 2048 x 256. BJ=128, 16 chunks, pair-unrolled (chunk c -> Plds[0],
// chunk c+1 -> Plds[1]) with NAMED register prefetch pairs — r5 fix: the r4
// A0[2]/D0[2] arrays indexed by runtime (c&1) were lowered to scratch
// (VGPR_Count=36, WRITE_SIZE 366 MB of scratch traffic). No arrays now.
// ---------------------------------------------------------------------------
__global__ __launch_bounds__(256) void k_attn(
    const int* __restrict__ adj, const unsigned short* __restrict__ hTf,
    const float* __restrict__ s_src, const float* __restrict__ s_dst,
    const unsigned int* __restrict__ Smax_u, float* __restrict__ accp,
    float* __restrict__ lp)
{
  const int t = threadIdx.x;
  const int wv = t >> 6, lane = t & 63;
  const int b = blockIdx.x;
  const int i0 = (b >> 2) * 16;
  const int jbase = (b & 3) * kJLen;
  const int pr = t >> 4, jb = t & 15;

  __shared__ unsigned short Plds[2][16][136];   // 8.7 KB

  const float S = fdec(*Smax_u);
  const float ssrc = s_src[i0 + pr];
  const float mr = lrelu(ssrc + S);             // >= every score in the row

  float l_acc = 0.f;
  f32x4 acc = {0.f, 0.f, 0.f, 0.f};

  const int4*   aptr = (const int4*)(adj + (size_t)(i0 + pr) * kN + jbase + jb * 8);
  const float4* dptr = (const float4*)(s_dst + jbase + jb * 8);
  const unsigned short* hbase = hTf + (size_t)(jbase >> 5) * 2048 + wv * 512 + (size_t)lane * 8;

  const int mrow = lane & 15, quad = lane >> 4;

  // named prefetch registers — chunk c (a) and c+1 (b); depth-2 rotation
  int4   A0a = aptr[0],  A1a = aptr[1];
  float4 D0a = dptr[0],  D1a = dptr[1];
  int4   A0b = aptr[32], A1b = aptr[33];
  float4 D0b = dptr[32], D1b = dptr[33];

  auto phase = [&](int c, int sbuf, int4& A0, int4& A1, float4& D0, float4& D1)
      __attribute__((always_inline)) {
    float pv[8];
    {
      const int* aa = (const int*)&A0;
      const float* dd = (const float*)&D0;
#pragma unroll
      for (int j = 0; j < 4; ++j) {
        const float e = lrelu(ssrc + dd[j]);
        pv[j] = aa[j] > 0 ? __expf(e - mr) : 0.f;
      }
      aa = (const int*)&A1; dd = (const float*)&D1;
#pragma unroll
      for (int j = 0; j < 4; ++j) {
        const float e = lrelu(ssrc + dd[j]);
        pv[4 + j] = aa[j] > 0 ? __expf(e - mr) : 0.f;
      }
    }
    bf16x8 ps;
#pragma unroll
    for (int j = 0; j < 8; ++j) {
      l_acc += pv[j];
      ps[j] = (short)f2bf(pv[j]);
    }
    *(bf16x8*)&Plds[sbuf][pr][jb * 8] = ps;

    // B-fragments for this chunk: issued pre-barrier (L2), used post-barrier
    const uint4 hv0 = *(const uint4*)(hbase + (size_t)(c * 4 + 0) * 2048);
    const uint4 hv1 = *(const uint4*)(hbase + (size_t)(c * 4 + 1) * 2048);
    const uint4 hv2 = *(const uint4*)(hbase + (size_t)(c * 4 + 2) * 2048);
    const uint4 hv3 = *(const uint4*)(hbase + (size_t)(c * 4 + 3) * 2048);

    // depth-2 adj/s_dst prefetch (chunk c+2 into this phase's registers)
    if (c + 2 < kChunks) {
      A0 = aptr[(c + 2) * 32]; A1 = aptr[(c + 2) * 32 + 1];
      D0 = dptr[(c + 2) * 32]; D1 = dptr[(c + 2) * 32 + 1];
    }
    __syncthreads();

    acc = __builtin_amdgcn_mfma_f32_16x16x32_bf16(
        *(const bf16x8*)&Plds[sbuf][mrow][0 * 32 + quad * 8], __builtin_bit_cast(bf16x8, hv0), acc, 0, 0, 0);
    acc = __builtin_amdgcn_mfma_f32_16x16x32_bf16(
        *(const bf16x8*)&Plds[sbuf][mrow][1 * 32 + quad * 8], __builtin_bit_cast(bf16x8, hv1), acc, 0, 0, 0);
    acc = __builtin_amdgcn_mfma_f32_16x16x32_bf16(
        *(const bf16x8*)&Plds[sbuf][mrow][2 * 32 + quad * 8], __builtin_bit_cast(bf16x8, hv2), acc, 0, 0, 0);
    acc = __builtin_amdgcn_mfma_f32_16x16x32_bf16(
        *(const bf16x8*)&Plds[sbuf][mrow][3 * 32 + quad * 8], __builtin_bit_cast(bf16x8, hv3), acc, 0, 0, 0);
    // no trailing barrier: the next phase writes the OTHER P buffer; this
    // buffer is rewritten only after the next barrier.
  };

  for (int c = 0; c < kChunks; c += 2) {
    phase(c,     0, A0a, A1a, D0a, D1a);
    phase(c + 1, 1, A0b, A1b, D0b, D1b);
  }

  // partial denominator: 16 lanes (same pr) reduce
  float lv = l_acc;
  lv += __shfl_xor(lv, 8, 64);
  lv += __shfl_xor(lv, 4, 64);
  lv += __shfl_xor(lv, 2, 64);
  lv += __shfl_xor(lv, 1, 64);
  if (jb == 0) lp[(size_t)b * 16 + pr] = lv;

  // partial PV tile: accp[b][row][col], row = quad*4+reg, col = wv*16+mrow
  float* ab = accp + (size_t)b * 16 * 64;
#pragma unroll
  for (int reg = 0; reg < 4; ++reg) {
    ab[(quad * 4 + reg) * 64 + wv * 16 + mrow] = acc[reg];
  }
}

// ---------------------------------------------------------------------------
// k_comb: out[i][f] = elu( (sum_q accp) / (sum_q lp) )
// ---------------------------------------------------------------------------
__global__ __launch_bounds__(256) void k_comb(const float* __restrict__ accp,
                                              const float* __restrict__ lp,
                                              float* __restrict__ out)
{
  const int gid = blockIdx.x * 256 + threadIdx.x;   // 0..524287
  const int i = gid >> 6, f = gid & 63;
  const int ib = i >> 4, il = i & 15;
  const int b0 = ib * kJSplit;
  float a = 0.f, l = 0.f;
#pragma unroll
  for (int q = 0; q < kJSplit; ++q) {
    a += accp[((size_t)(b0 + q) * 16 + il) * 64 + f];
    l += lp[(size_t)(b0 + q) * 16 + il];
  }
  float v = a / l;
  v = v > 0.f ? v : __expf(v) - 1.f;
  out[gid] = v;
}

extern "C" void kernel_launch(void* const* d_in, const int* in_sizes, int n_in,
                              void* d_out, int out_size, void* d_ws, size_t ws_size,
                              hipStream_t stream) {
  const float* X   = (const float*)d_in[0];   // [8192][512]
  const int*   adj = (const int*)d_in[1];     // [8192][8192]
  const float* W   = (const float*)d_in[2];   // [512][64]
  const float* A   = (const float*)d_in[3];   // [128]
  float* out = (float*)d_out;                 // [8192][64] fp32

  char* ws = (char*)d_ws;
  unsigned short* hTf = (unsigned short*)ws;  ws += (size_t)kN * kFout * 2;    // 1 MB
  float* WT    = (float*)ws;                  ws += (size_t)kFout * kFin * 4;  // 128 KB
  float* s_src = (float*)ws;                  ws += kN * 4;
  float* s_dst = (float*)ws;                  ws += kN * 4;
  unsigned int* Smax_u = (unsigned int*)ws;   ws += 256;
  float* accp  = (float*)ws;                  ws += (size_t)(kN / 16) * kJSplit * 16 * 64 * 4; // 8 MB
  float* lp    = (float*)ws;                  // 128 KB

  k_wt    <<<kFin * kFout / 256, 256, 0, stream>>>(W, WT, Smax_u);
  k_linear<<<kN / 16, 256, 0, stream>>>(X, WT, A, hTf, s_src, s_dst, Smax_u);
  k_attn  <<<(kN / 16) * kJSplit, 256, 0, stream>>>(adj, hTf, s_src, s_dst, Smax_u, accp, lp);
  k_comb  <<<kN * kFout / 256, 256, 0, stream>>>(accp, lp, out);
}